// Round 1
// baseline (190.137 us; speedup 1.0000x reference)
//
#include <hip/hip_runtime.h>
#include <hip/hip_bf16.h>
#include <stdint.h>

// Q8_0 dequant linear: y = x @ W^T + bias, W[o,i] = q[o,i]*scales[o,i/32]
// M = B*S = 4096, K = I = 4096, N = O = 4096.
// Plan: (1) x fp32 -> bf16, (2) W dequant -> bf16, (3) m97-structure bf16 MFMA GEMM.

#define M_DIM 4096
#define N_DIM 4096
#define K_DIM 4096
#define NB_SC 128   // scales per row (K/32)

#define BM 128
#define BN 128
#define BK 64

typedef __attribute__((ext_vector_type(8))) short bf16x8;
typedef __attribute__((ext_vector_type(4))) float f32x4;

__device__ __forceinline__ unsigned short f2bf(float f) {
  // round-to-nearest-even bf16 (finite inputs only)
  unsigned int u = __float_as_uint(f);
  u += 0x7fffu + ((u >> 16) & 1u);
  return (unsigned short)(u >> 16);
}

__device__ __forceinline__ void gload_lds16(const void* gsrc, void* ldsdst) {
  // async global->LDS, 16B per lane; LDS dest is wave-uniform base + lane*16
  __builtin_amdgcn_global_load_lds(
      (__attribute__((address_space(1))) void*)(uintptr_t)gsrc,
      (__attribute__((address_space(3))) void*)(uint32_t)(uintptr_t)ldsdst,
      16, 0, 0);
}

// ---------------- prep kernels ----------------

__global__ void cvt_x_kernel(const float* __restrict__ x, unsigned short* __restrict__ xb) {
  const size_t total8 = (size_t)M_DIM * K_DIM / 8;
  for (size_t t = (size_t)blockIdx.x * blockDim.x + threadIdx.x; t < total8;
       t += (size_t)gridDim.x * blockDim.x) {
    size_t base = t * 8;
    const float4* p = (const float4*)(x + base);
    float4 a = p[0], b = p[1];
    union { unsigned short u[8]; uint4 v; } r;
    r.u[0] = f2bf(a.x); r.u[1] = f2bf(a.y); r.u[2] = f2bf(a.z); r.u[3] = f2bf(a.w);
    r.u[4] = f2bf(b.x); r.u[5] = f2bf(b.y); r.u[6] = f2bf(b.z); r.u[7] = f2bf(b.w);
    *(uint4*)(xb + base) = r.v;
  }
}

__global__ void dequant_kernel(const int* __restrict__ q, const float* __restrict__ sc,
                               unsigned short* __restrict__ wb) {
  const size_t total8 = (size_t)N_DIM * K_DIM / 8;
  for (size_t t = (size_t)blockIdx.x * blockDim.x + threadIdx.x; t < total8;
       t += (size_t)gridDim.x * blockDim.x) {
    size_t base = t * 8;
    int o = (int)(base >> 12);        // row (O dim)
    int i = (int)(base & 4095);       // col (I dim); 8 consecutive stay in one 32-block
    float s = sc[(o << 7) + (i >> 5)];
    const int4* qp = (const int4*)(q + base);
    int4 q0 = qp[0], q1 = qp[1];
    union { unsigned short u[8]; uint4 v; } r;
    r.u[0] = f2bf((float)q0.x * s); r.u[1] = f2bf((float)q0.y * s);
    r.u[2] = f2bf((float)q0.z * s); r.u[3] = f2bf((float)q0.w * s);
    r.u[4] = f2bf((float)q1.x * s); r.u[5] = f2bf((float)q1.y * s);
    r.u[6] = f2bf((float)q1.z * s); r.u[7] = f2bf((float)q1.w * s);
    *(uint4*)(wb + base) = r.v;
  }
}

// ---------------- GEMM: C[m][n] = sum_k A[m][k]*Bt[n][k] + bias[n] ----------------
// m97 structure: 128x128 tile, BK=64, 4 waves (2x2), 16x16x32 bf16 MFMA,
// global_load_lds width-16 staging, 2-barrier K-loop.

__global__ void gemm_bt(const unsigned short* __restrict__ A,
                        const unsigned short* __restrict__ Bt,
                        const float* __restrict__ bias,
                        float* __restrict__ C) {
  __shared__ unsigned short As[BM * BK];  // [128][64] row-major
  __shared__ unsigned short Bs[BN * BK];

  const int tid  = threadIdx.x;
  const int wave = tid >> 6;
  const int lane = tid & 63;

  // XCD-aware swizzle (nwg = 1024, divisible by 8 -> bijective)
  const int bid = blockIdx.x;
  const int cpx = gridDim.x >> 3;
  const int swz = (bid & 7) * cpx + (bid >> 3);
  const int bm0 = (swz >> 5) * BM;   // N/BN = 32 tiles per row
  const int bn0 = (swz & 31) * BN;

  const int wr = wave >> 1;          // 2x2 wave grid, each wave owns 64x64
  const int wc = wave & 1;

  f32x4 acc[4][4] = {};

  // MFMA fragment addressing: row = lane&15, k-base = (lane>>4)*8
  const int frow = lane & 15;
  const int fk   = (lane >> 4) * 8;

  // staging: per wave 4 chunks of 1KB each for A and B
  // chunk c covers LDS bf16 flat [c*512, c*512+512): rows [c*8, c*8+8), all 64 k
  const int srow = (lane >> 3);       // 8 lanes per row
  const int sk   = (lane & 7) * 8;    // 8 bf16 = 16B per lane

  for (int kt = 0; kt < K_DIM; kt += BK) {
#pragma unroll
    for (int j = 0; j < 4; ++j) {
      int chunk = wave * 4 + j;
      int row = chunk * 8 + srow;
      gload_lds16(A  + (size_t)(bm0 + row) * K_DIM + kt + sk, &As[chunk * 512]);
      gload_lds16(Bt + (size_t)(bn0 + row) * K_DIM + kt + sk, &Bs[chunk * 512]);
    }
    __syncthreads();   // compiler drains vmcnt before barrier

#pragma unroll
    for (int kk = 0; kk < BK; kk += 32) {
      bf16x8 a[4], b[4];
#pragma unroll
      for (int mi = 0; mi < 4; ++mi)
        a[mi] = *(const bf16x8*)&As[(wr * 64 + mi * 16 + frow) * BK + kk + fk];
#pragma unroll
      for (int ni = 0; ni < 4; ++ni)
        b[ni] = *(const bf16x8*)&Bs[(wc * 64 + ni * 16 + frow) * BK + kk + fk];
#pragma unroll
      for (int mi = 0; mi < 4; ++mi)
#pragma unroll
        for (int ni = 0; ni < 4; ++ni)
          acc[mi][ni] = __builtin_amdgcn_mfma_f32_16x16x32_bf16(a[mi], b[ni], acc[mi][ni], 0, 0, 0);
    }
    __syncthreads();
  }

  // epilogue: C/D layout col = lane&15 (n), row = (lane>>4)*4 + r (m)
#pragma unroll
  for (int ni = 0; ni < 4; ++ni) {
    int n = bn0 + wc * 64 + ni * 16 + (lane & 15);
    float bv = bias[n];
#pragma unroll
    for (int mi = 0; mi < 4; ++mi) {
      int mbase = bm0 + wr * 64 + mi * 16 + (lane >> 4) * 4;
#pragma unroll
      for (int r = 0; r < 4; ++r) {
        C[(size_t)(mbase + r) * N_DIM + n] = acc[mi][ni][r] + bv;
      }
    }
  }
}

// ---------------- naive fallback (only if ws too small) ----------------

__global__ void naive_kernel(const float* __restrict__ x, const int* __restrict__ q,
                             const float* __restrict__ sc, const float* __restrict__ bias,
                             float* __restrict__ out) {
  size_t idx = (size_t)blockIdx.x * blockDim.x + threadIdx.x;
  if (idx >= (size_t)M_DIM * N_DIM) return;
  int n = (int)(idx & (N_DIM - 1));
  size_t m = idx >> 12;
  float acc = 0.f;
  for (int k = 0; k < K_DIM; k += 32) {
    float s = sc[n * NB_SC + (k >> 5)];
    float part = 0.f;
    for (int j = 0; j < 32; ++j)
      part += x[m * K_DIM + k + j] * (float)q[(size_t)n * K_DIM + k + j];
    acc += part * s;
  }
  out[idx] = acc + bias[n];
}

// ---------------- launch ----------------

extern "C" void kernel_launch(void* const* d_in, const int* in_sizes, int n_in,
                              void* d_out, int out_size, void* d_ws, size_t ws_size,
                              hipStream_t stream) {
  const float* x    = (const float*)d_in[0];
  const int*   q    = (const int*)d_in[1];
  const float* sc   = (const float*)d_in[2];
  const float* bias = (const float*)d_in[3];
  float* out = (float*)d_out;

  const size_t elems = (size_t)M_DIM * K_DIM;          // 16,777,216
  const size_t need  = 2 * elems * sizeof(unsigned short);  // 64 MB

  if (ws_size >= need) {
    unsigned short* xb = (unsigned short*)d_ws;
    unsigned short* wb = xb + elems;
    hipLaunchKernelGGL(cvt_x_kernel,  dim3(2048), dim3(256), 0, stream, x, xb);
    hipLaunchKernelGGL(dequant_kernel, dim3(2048), dim3(256), 0, stream, q, sc, wb);
    hipLaunchKernelGGL(gemm_bt, dim3((M_DIM / BM) * (N_DIM / BN)), dim3(256), 0, stream,
                       xb, wb, bias, out);
  } else {
    hipLaunchKernelGGL(naive_kernel, dim3((M_DIM * N_DIM) / 256), dim3(256), 0, stream,
                       x, q, sc, bias, out);
  }
}

// Round 2
// 146.483 us; speedup vs baseline: 1.2980x; 1.2980x over previous
//
#include <hip/hip_runtime.h>
#include <hip/hip_bf16.h>
#include <stdint.h>

// Q8_0 dequant linear: y = x @ W^T + bias.  M=N=K=4096.
// (1) x fp32->bf16, (2) W dequant->bf16, (3) 256x256-tile 8-phase bf16 MFMA GEMM
//     (m201 template: counted vmcnt, st-swizzled LDS, setprio around MFMA).

#define M_DIM 4096
#define N_DIM 4096
#define K_DIM 4096
#define NB_SC 128

#define BM 256
#define BN 256
#define BK 64
#define NT (K_DIM / BK)   // 64 K-tiles

typedef __attribute__((ext_vector_type(8))) short bf16x8;
typedef __attribute__((ext_vector_type(4))) float f32x4;

__device__ __forceinline__ unsigned short f2bf(float f) {
  unsigned int u = __float_as_uint(f);
  u += 0x7fffu + ((u >> 16) & 1u);
  return (unsigned short)(u >> 16);
}

__device__ __forceinline__ void gload_lds16(const void* gsrc, void* ldsdst) {
  __builtin_amdgcn_global_load_lds(
      (__attribute__((address_space(1))) void*)(uintptr_t)gsrc,
      (__attribute__((address_space(3))) void*)(uint32_t)(uintptr_t)ldsdst,
      16, 0, 0);
}

// ---------------- prep kernels ----------------

__global__ void cvt_x_kernel(const float* __restrict__ x, unsigned short* __restrict__ xb) {
  const size_t total8 = (size_t)M_DIM * K_DIM / 8;
  for (size_t t = (size_t)blockIdx.x * blockDim.x + threadIdx.x; t < total8;
       t += (size_t)gridDim.x * blockDim.x) {
    size_t base = t * 8;
    const float4* p = (const float4*)(x + base);
    float4 a = p[0], b = p[1];
    union { unsigned short u[8]; uint4 v; } r;
    r.u[0] = f2bf(a.x); r.u[1] = f2bf(a.y); r.u[2] = f2bf(a.z); r.u[3] = f2bf(a.w);
    r.u[4] = f2bf(b.x); r.u[5] = f2bf(b.y); r.u[6] = f2bf(b.z); r.u[7] = f2bf(b.w);
    *(uint4*)(xb + base) = r.v;
  }
}

__global__ void dequant_kernel(const int* __restrict__ q, const float* __restrict__ sc,
                               unsigned short* __restrict__ wb) {
  const size_t total8 = (size_t)N_DIM * K_DIM / 8;
  for (size_t t = (size_t)blockIdx.x * blockDim.x + threadIdx.x; t < total8;
       t += (size_t)gridDim.x * blockDim.x) {
    size_t base = t * 8;
    int o = (int)(base >> 12);
    int i = (int)(base & 4095);
    float s = sc[(o << 7) + (i >> 5)];
    const int4* qp = (const int4*)(q + base);
    int4 q0 = qp[0], q1 = qp[1];
    union { unsigned short u[8]; uint4 v; } r;
    r.u[0] = f2bf((float)q0.x * s); r.u[1] = f2bf((float)q0.y * s);
    r.u[2] = f2bf((float)q0.z * s); r.u[3] = f2bf((float)q0.w * s);
    r.u[4] = f2bf((float)q1.x * s); r.u[5] = f2bf((float)q1.y * s);
    r.u[6] = f2bf((float)q1.z * s); r.u[7] = f2bf((float)q1.w * s);
    *(uint4*)(wb + base) = r.v;
  }
}

// ---------------- 256x256 8-phase GEMM ----------------
// LDS tile [256][64] bf16, 128B rows = 8 x 16B granules. Swizzle: logical
// granule g of row r stored at granule g^(r&7). gload_lds dest is linear;
// source address pre-applies the inverse permutation (same involution).

__device__ __forceinline__ bf16x8 lds_frag(const unsigned short* t, int r, int k0) {
  return *(const bf16x8*)(t + r * 64 + ((((k0) >> 3) ^ (r & 7)) << 3));
}

// Stage one half-tile (128 rows x 64 cols): per wave 2 x global_load_lds
// (1 KB each, 8 rows). Lane l sources row rbase+(l>>3), granule (l&7)^(l>>3).
__device__ __forceinline__ void stage_half(const unsigned short* __restrict__ g,
                                           unsigned short* lds, int hr0, int row0,
                                           int ktT, int w, int l) {
#pragma unroll
  for (int j = 0; j < 2; ++j) {
    const int rbase = hr0 + w * 16 + j * 8;
    const int r = rbase + (l >> 3);
    const int k = ((l & 7) ^ (l >> 3)) << 3;
    gload_lds16(g + (size_t)(row0 + r) * K_DIM + ktT + k, lds + rbase * 64);
  }
}

__device__ __forceinline__ void read_a(const unsigned short* Ac, int r0, int frow, int fk,
                                       bf16x8 (&af)[2][2]) {
#pragma unroll
  for (int q = 0; q < 2; ++q)
#pragma unroll
    for (int kk = 0; kk < 2; ++kk)
      af[q][kk] = lds_frag(Ac, r0 + q * 16 + frow, kk * 32 + fk);
}

__device__ __forceinline__ void mfma_quad(const bf16x8 (&af)[2][2], const bf16x8 (&bf)[4][2],
                                          f32x4 (&acc)[8][4], int q0) {
  __builtin_amdgcn_s_setprio(1);
#pragma unroll
  for (int q = 0; q < 2; ++q)
#pragma unroll
    for (int ni = 0; ni < 4; ++ni)
#pragma unroll
      for (int kk = 0; kk < 2; ++kk)
        acc[q0 + q][ni] =
            __builtin_amdgcn_mfma_f32_16x16x32_bf16(af[q][kk], bf[ni][kk], acc[q0 + q][ni], 0, 0, 0);
  __builtin_amdgcn_s_setprio(0);
}

__global__ __launch_bounds__(512, 2) void gemm256(const unsigned short* __restrict__ A,
                                                  const unsigned short* __restrict__ B,
                                                  const float* __restrict__ bias,
                                                  float* __restrict__ C) {
  __shared__ unsigned short AsB[2 * BM * BK];   // 64 KiB (double-buffered)
  __shared__ unsigned short BsB[2 * BN * BK];   // 64 KiB

  const int tid = threadIdx.x;
  const int w = tid >> 6;          // 8 waves: 2 (M) x 4 (N)
  const int l = tid & 63;
  const int wm = w >> 2;
  const int wn = w & 3;
  const int frow = l & 15;
  const int fk = (l >> 4) * 8;

  // XCD-aware swizzle: 256 blocks, 256%8==0 -> bijective
  const int bid = blockIdx.x;
  const int cpx = gridDim.x >> 3;
  const int swz = (bid & 7) * cpx + (bid >> 3);
  const int bm0 = (swz >> 4) * BM;
  const int bn0 = (swz & 15) * BN;

  f32x4 acc[8][4] = {};

  // Prologue: tile0 {B0,B1,A0,A1} -> buf0; tile1 {B0,B1,A0} -> buf1.
  stage_half(B, BsB, 0, bn0, 0, w, l);
  stage_half(B, BsB, 128, bn0, 0, w, l);
  stage_half(A, AsB, 0, bm0, 0, w, l);
  stage_half(A, AsB, 128, bm0, 0, w, l);
  asm volatile("s_waitcnt vmcnt(4)" ::: "memory");
  stage_half(B, BsB + BN * BK, 0, bn0, BK, w, l);
  stage_half(B, BsB + BN * BK, 128, bn0, BK, w, l);
  stage_half(A, AsB + BM * BK, 0, bm0, BK, w, l);
  asm volatile("s_waitcnt vmcnt(6)" ::: "memory");   // tile0 fully landed
  __builtin_amdgcn_s_barrier();

  for (int t = 0; t < NT; ++t) {
    const int buf = t & 1;
    const unsigned short* Ac = AsB + buf * (BM * BK);
    const unsigned short* Bc = BsB + buf * (BN * BK);
    unsigned short* Aw = AsB + buf * (BM * BK);        // tile t+2 halves
    unsigned short* Bw = BsB + buf * (BN * BK);
    unsigned short* An = AsB + (buf ^ 1) * (BM * BK);  // tile t+1 last half

    bf16x8 bfrag[4][2];
    bf16x8 af[2][2];

    // phase 0: B(8 reads) + A q0; stage A1 of t+1 (other buffer)
#pragma unroll
    for (int ni = 0; ni < 4; ++ni)
#pragma unroll
      for (int kk = 0; kk < 2; ++kk)
        bfrag[ni][kk] = lds_frag(Bc, wn * 64 + ni * 16 + frow, kk * 32 + fk);
    read_a(Ac, wm * 128 + 0, frow, fk, af);
    if (t + 1 < NT) stage_half(A, An, 128, bm0, (t + 1) * BK, w, l);
    __builtin_amdgcn_s_barrier();
    mfma_quad(af, bfrag, acc, 0);
    __builtin_amdgcn_s_barrier();

    // phase 1: A q1; stage B0 of t+2 (B fully consumed in phase 0)
    read_a(Ac, wm * 128 + 32, frow, fk, af);
    if (t + 2 < NT) stage_half(B, Bw, 0, bn0, (t + 2) * BK, w, l);
    __builtin_amdgcn_s_barrier();
    mfma_quad(af, bfrag, acc, 2);
    __builtin_amdgcn_s_barrier();

    // phase 2: A q2; stage B1 of t+2
    read_a(Ac, wm * 128 + 64, frow, fk, af);
    if (t + 2 < NT) stage_half(B, Bw, 128, bn0, (t + 2) * BK, w, l);
    __builtin_amdgcn_s_barrier();
    mfma_quad(af, bfrag, acc, 4);
    __builtin_amdgcn_s_barrier();

    // phase 3: A q3; stage A0 of t+2; counted vmcnt at tile boundary
    read_a(Ac, wm * 128 + 96, frow, fk, af);
    if (t + 2 < NT) stage_half(A, Aw, 0, bm0, (t + 2) * BK, w, l);
    __builtin_amdgcn_s_barrier();
    mfma_quad(af, bfrag, acc, 6);
    if (t < NT - 2)
      asm volatile("s_waitcnt vmcnt(6)" ::: "memory");  // tile t+1 landed; 3 half-tiles in flight
    else
      asm volatile("s_waitcnt vmcnt(0)" ::: "memory");  // epilogue drain
    __builtin_amdgcn_s_barrier();
  }

  // Epilogue: C/D layout col=lane&15 (n), row=(lane>>4)*4+r (m)
#pragma unroll
  for (int ni = 0; ni < 4; ++ni) {
    int n = bn0 + wn * 64 + ni * 16 + (l & 15);
    float bv = bias[n];
#pragma unroll
    for (int mi = 0; mi < 8; ++mi) {
      int mbase = bm0 + wm * 128 + mi * 16 + (l >> 4) * 4;
#pragma unroll
      for (int r = 0; r < 4; ++r)
        C[(size_t)(mbase + r) * N_DIM + n] = acc[mi][ni][r] + bv;
    }
  }
}

// ---------------- naive fallback ----------------

__global__ void naive_kernel(const float* __restrict__ x, const int* __restrict__ q,
                             const float* __restrict__ sc, const float* __restrict__ bias,
                             float* __restrict__ out) {
  size_t idx = (size_t)blockIdx.x * blockDim.x + threadIdx.x;
  if (idx >= (size_t)M_DIM * N_DIM) return;
  int n = (int)(idx & (N_DIM - 1));
  size_t m = idx >> 12;
  float acc = 0.f;
  for (int k = 0; k < K_DIM; k += 32) {
    float s = sc[n * NB_SC + (k >> 5)];
    float part = 0.f;
    for (int j = 0; j < 32; ++j)
      part += x[m * K_DIM + k + j] * (float)q[(size_t)n * K_DIM + k + j];
    acc += part * s;
  }
  out[idx] = acc + bias[n];
}

// ---------------- launch ----------------

extern "C" void kernel_launch(void* const* d_in, const int* in_sizes, int n_in,
                              void* d_out, int out_size, void* d_ws, size_t ws_size,
                              hipStream_t stream) {
  const float* x    = (const float*)d_in[0];
  const int*   q    = (const int*)d_in[1];
  const float* sc   = (const float*)d_in[2];
  const float* bias = (const float*)d_in[3];
  float* out = (float*)d_out;

  const size_t elems = (size_t)M_DIM * K_DIM;
  const size_t need  = 2 * elems * sizeof(unsigned short);

  if (ws_size >= need) {
    unsigned short* xb = (unsigned short*)d_ws;
    unsigned short* wb = xb + elems;
    hipLaunchKernelGGL(cvt_x_kernel,   dim3(2048), dim3(256), 0, stream, x, xb);
    hipLaunchKernelGGL(dequant_kernel, dim3(2048), dim3(256), 0, stream, q, sc, wb);
    hipLaunchKernelGGL(gemm256, dim3((M_DIM / BM) * (N_DIM / BN)), dim3(512), 0, stream,
                       xb, wb, bias, out);
  } else {
    hipLaunchKernelGGL(naive_kernel, dim3((M_DIM * N_DIM) / 256), dim3(256), 0, stream,
                       x, q, sc, bias, out);
  }
}